// Round 1
// baseline (92.885 us; speedup 1.0000x reference)
//
#include <hip/hip_runtime.h>
#include <hip/hip_bf16.h>

// OcrEmbedding: EmbeddingBag-sum.
//   subtoken_ids: int32 [B=32, T=512, S=4]  (B*T = 16384 bags, S=4 lookups each)
//   table:        fp32  [V=50000, D=256]
//   out:          fp32  [B, T, D] = sum_s table[ids[b,t,s]]  with row 0 == zero
//
// One 64-lane wave per output row; each lane holds a float4 (64*4 = 256 = D).
// Indices are wave-uniform -> the id!=0 branch never diverges.

#define PAD_IDX 0
#define D_MODEL 256
#define NUM_ROWS (32 * 512)   // B*T

__global__ __launch_bounds__(256) void ocr_embedding_bag_kernel(
    const int* __restrict__ ids,      // [NUM_ROWS, 4]
    const float* __restrict__ table,  // [V, 256]
    float* __restrict__ out)          // [NUM_ROWS, 256]
{
    const int gtid = blockIdx.x * blockDim.x + threadIdx.x;
    const int row  = gtid >> 6;        // wave per bag
    const int lane = threadIdx.x & 63;
    if (row >= NUM_ROWS) return;

    // All 64 lanes load the same 16B -> one cache line, broadcast.
    const int4 id4 = ((const int4*)ids)[row];

    const float4* __restrict__ tab4 = (const float4*)table;  // [V, 64]

    float4 acc = make_float4(0.f, 0.f, 0.f, 0.f);

    // Wave-uniform branches; loads of distinct s are independent -> ILP.
    if (id4.x != PAD_IDX) {
        float4 v = tab4[(size_t)id4.x * 64 + lane];
        acc.x += v.x; acc.y += v.y; acc.z += v.z; acc.w += v.w;
    }
    if (id4.y != PAD_IDX) {
        float4 v = tab4[(size_t)id4.y * 64 + lane];
        acc.x += v.x; acc.y += v.y; acc.z += v.z; acc.w += v.w;
    }
    if (id4.z != PAD_IDX) {
        float4 v = tab4[(size_t)id4.z * 64 + lane];
        acc.x += v.x; acc.y += v.y; acc.z += v.z; acc.w += v.w;
    }
    if (id4.w != PAD_IDX) {
        float4 v = tab4[(size_t)id4.w * 64 + lane];
        acc.x += v.x; acc.y += v.y; acc.z += v.z; acc.w += v.w;
    }

    ((float4*)out)[(size_t)row * 64 + lane] = acc;
}

extern "C" void kernel_launch(void* const* d_in, const int* in_sizes, int n_in,
                              void* d_out, int out_size, void* d_ws, size_t ws_size,
                              hipStream_t stream) {
    const int*   ids   = (const int*)d_in[0];
    const float* table = (const float*)d_in[1];
    float*       out   = (float*)d_out;

    // 16384 rows * 64 lanes = 1,048,576 threads; 256/block -> 4096 blocks.
    dim3 block(256);
    dim3 grid((NUM_ROWS * 64) / 256);
    ocr_embedding_bag_kernel<<<grid, block, 0, stream>>>(ids, table, out);
}

// Round 2
// 92.704 us; speedup vs baseline: 1.0020x; 1.0020x over previous
//
#include <hip/hip_runtime.h>
#include <hip/hip_bf16.h>

// OcrEmbedding: EmbeddingBag-sum.
//   subtoken_ids: int32 [B=32, T=512, S=4]  (B*T = 16384 bags, S=4 lookups each)
//   table:        fp32  [V=50000, D=256]
//   out:          fp32  [B, T, D] = sum_s table[ids[b,t,s]]  with row 0 == zero
//
// One 64-lane wave per W=4 bags; each lane holds a float4 slice (64*4 = 256 = D).
// All 16 row-gathers are issued before any accumulation (4x MLP vs the 1-bag
// version), and pad-id masking is branch-free (cndmask) so nothing stalls issue.

#define PAD_IDX 0
#define NUM_ROWS (32 * 512)   // B*T bags
#define W 4                   // bags per wave

__global__ __launch_bounds__(256) void ocr_embedding_bag_kernel(
    const int* __restrict__ ids,      // [NUM_ROWS, 4]
    const float* __restrict__ table,  // [V, 256]
    float* __restrict__ out)          // [NUM_ROWS, 256]
{
    const int wave = (blockIdx.x * blockDim.x + threadIdx.x) >> 6;
    const int lane = threadIdx.x & 63;
    const int row0 = wave * W;       // first bag of this wave

    const float4* __restrict__ tab4 = (const float4*)table;   // [V, 64]
    const int4*   __restrict__ ids4 = (const int4*)ids;       // [NUM_ROWS]

    // 1) Issue all W uniform index loads (each is one broadcast cache line).
    int4 id[W];
#pragma unroll
    for (int i = 0; i < W; ++i) id[i] = ids4[row0 + i];

    // 2) Issue all W*4 = 16 row gathers back-to-back (unconditional -> the
    //    compiler can keep them all in flight; 16 x 1KiB outstanding per wave).
    float4 v[W][4];
#pragma unroll
    for (int i = 0; i < W; ++i) {
        v[i][0] = tab4[(size_t)id[i].x * 64 + lane];
        v[i][1] = tab4[(size_t)id[i].y * 64 + lane];
        v[i][2] = tab4[(size_t)id[i].z * 64 + lane];
        v[i][3] = tab4[(size_t)id[i].w * 64 + lane];
    }

    // 3) Branch-free masked accumulate + store (VALU is idle; selects are free).
#pragma unroll
    for (int i = 0; i < W; ++i) {
        const int4 d = id[i];
        float4 acc = make_float4(0.f, 0.f, 0.f, 0.f);
        if (true) {
            const float mx = (d.x != PAD_IDX) ? 1.f : 0.f;
            const float my = (d.y != PAD_IDX) ? 1.f : 0.f;
            const float mz = (d.z != PAD_IDX) ? 1.f : 0.f;
            const float mw = (d.w != PAD_IDX) ? 1.f : 0.f;
            acc.x = mx * v[i][0].x + my * v[i][1].x + mz * v[i][2].x + mw * v[i][3].x;
            acc.y = mx * v[i][0].y + my * v[i][1].y + mz * v[i][2].y + mw * v[i][3].y;
            acc.z = mx * v[i][0].z + my * v[i][1].z + mz * v[i][2].z + mw * v[i][3].z;
            acc.w = mx * v[i][0].w + my * v[i][1].w + mz * v[i][2].w + mw * v[i][3].w;
        }
        ((float4*)out)[(size_t)(row0 + i) * 64 + lane] = acc;
    }
}

extern "C" void kernel_launch(void* const* d_in, const int* in_sizes, int n_in,
                              void* d_out, int out_size, void* d_ws, size_t ws_size,
                              hipStream_t stream) {
    const int*   ids   = (const int*)d_in[0];
    const float* table = (const float*)d_in[1];
    float*       out   = (float*)d_out;

    // 16384 bags / 4 per wave = 4096 waves; 4 waves/block -> 1024 blocks.
    dim3 block(256);
    dim3 grid(NUM_ROWS / (W * 4));
    ocr_embedding_bag_kernel<<<grid, block, 0, stream>>>(ids, table, out);
}